// Round 14
// baseline (189.259 us; speedup 1.0000x reference)
//
#include <hip/hip_runtime.h>

typedef unsigned short u16;
typedef __bf16 bf16x8 __attribute__((ext_vector_type(8)));
typedef unsigned short u16x8 __attribute__((ext_vector_type(8)));
typedef unsigned short u16x4 __attribute__((ext_vector_type(4)));
typedef float f32x4 __attribute__((ext_vector_type(4)));

#define MFMA16(a, b, c) __builtin_amdgcn_mfma_f32_16x16x32_bf16((a), (b), (c), 0, 0, 0)

#define WAVE_LDS_FENCE() do { \
  asm volatile("s_waitcnt lgkmcnt(0)" ::: "memory"); \
  __builtin_amdgcn_sched_barrier(0); \
} while (0)

#define RAW_BARRIER() do { \
  __builtin_amdgcn_sched_barrier(0); \
  __builtin_amdgcn_s_barrier(); \
  __builtin_amdgcn_sched_barrier(0); \
} while (0)

#define TOP_BARRIER() do { \
  asm volatile("s_waitcnt lgkmcnt(0)" ::: "memory"); \
  RAW_BARRIER(); \
} while (0)

#define PIPE_WAIT(N) do { \
  asm volatile("s_waitcnt vmcnt(" #N ")" ::: "memory"); \
  __builtin_amdgcn_sched_barrier(0); \
  __builtin_amdgcn_s_barrier(); \
  __builtin_amdgcn_sched_barrier(0); \
} while (0)

#define GLDS(gp, lp) __builtin_amdgcn_global_load_lds( \
    (const __attribute__((address_space(1))) unsigned int*)(gp), \
    (__attribute__((address_space(3))) unsigned int*)(lp), 16, 0, 0)

__device__ __forceinline__ u16 f2b(float f) {
  unsigned u = __float_as_uint(f);
  u += 0x7fffu + ((u >> 16) & 1u);   // RNE; inputs finite
  return (u16)(u >> 16);
}
__device__ __forceinline__ float b2f(u16 h) {
  return __uint_as_float(((unsigned)h) << 16);
}

// ---------------- fused converts (x, Wqkv, Wo) ----------------
__global__ void cvt_all(const float* __restrict__ x, u16* __restrict__ xb,
                        const float* __restrict__ w1, u16* __restrict__ w1b,
                        const float* __restrict__ w2, u16* __restrict__ w2b) {
  int i = blockIdx.x * blockDim.x + threadIdx.x;
  const float* s; u16* d; int off;
  if (i < 1048576)      { s = x;  d = xb;  off = i; }
  else if (i < 1835008) { s = w1; d = w1b; off = i - 1048576; }
  else                  { s = w2; d = w2b; off = i - 1835008; }
  float4 v = *(const float4*)(s + (size_t)off * 4);
  *(ushort4*)(d + (size_t)off * 4) = make_ushort4(f2b(v.x), f2b(v.y), f2b(v.z), f2b(v.w));
}

// F[n][m][d] = Er[n][(2048 - m) % 2048][d]
__global__ void build_F(const float* __restrict__ Er, u16* __restrict__ Fb) {
  int i = blockIdx.x * blockDim.x + threadIdx.x;
  int base = i * 4;
  int d = base & 63;
  int m = (base >> 6) & 1023;
  int n = base >> 16;
  int sm = (2048 - m) & 2047;
  float4 v = *(const float4*)(Er + ((size_t)(n * 2048 + sm) * 64 + d));
  *(ushort4*)(Fb + (size_t)base) = make_ushort4(f2b(v.x), f2b(v.y), f2b(v.z), f2b(v.w));
}

// ---------------- QKV GEMM: 3-buf counted-vmcnt pipeline, BK=32 (R10-exact, frozen) ----------------
__global__ __launch_bounds__(256) void gemm_qkv(const u16* __restrict__ A, const u16* __restrict__ Bw,
                                                const float* __restrict__ bias,
                                                u16* __restrict__ Qo, u16* __restrict__ Ko,
                                                u16* __restrict__ Vt) {
  __shared__ u16 As[3][4][128][8];
  __shared__ u16 Bs[3][4][128][8];
  const int orig = blockIdx.y * 24 + blockIdx.x;   // gridDim = (24, 32)
  const int xcd = orig & 7, q = orig >> 3;         // 96 blocks/XCD
  const int mt = ((xcd >> 1) << 3) + q / 12;
  const int nt = (xcd & 1) * 12 + q % 12;
  const int m0 = mt * 128, n0 = nt * 128;
  const int t = threadIdx.x, lane = t & 63, w = t >> 6;
  const int wr = w >> 1, wc = w & 1;
  const int l16 = lane & 15, lg = lane >> 4;
  f32x4 acc[4][4] = {};
  const int r0 = t & 127, g0 = t >> 7;
  const int g1 = g0 + 2;

#define STAGE(buf, k0) do { \
    GLDS(&A[(size_t)(m0 + r0) * 1024 + (k0) + g0 * 8], &As[buf][g0][r0][0]); \
    GLDS(&A[(size_t)(m0 + r0) * 1024 + (k0) + g1 * 8], &As[buf][g1][r0][0]); \
    GLDS(&Bw[(size_t)(n0 + r0) * 1024 + (k0) + g0 * 8], &Bs[buf][g0][r0][0]); \
    GLDS(&Bw[(size_t)(n0 + r0) * 1024 + (k0) + g1 * 8], &Bs[buf][g1][r0][0]); \
  } while (0)

  STAGE(0, 0);
  STAGE(1, 32);

  int buf = 0;
  for (int kt = 0; kt < 32; ++kt) {
    if (kt < 31) PIPE_WAIT(4); else PIPE_WAIT(0);
    if (kt < 30) {
      int nb = buf + 2; if (nb >= 3) nb -= 3;
      STAGE(nb, (kt + 2) * 32);
      __builtin_amdgcn_sched_barrier(0);
    }
    bf16x8 af[4], bfr[4];
#pragma unroll
    for (int m = 0; m < 4; ++m) af[m] = *(const bf16x8*)&As[buf][lg][wr * 64 + m * 16 + l16][0];
#pragma unroll
    for (int n = 0; n < 4; ++n) bfr[n] = *(const bf16x8*)&Bs[buf][lg][wc * 64 + n * 16 + l16][0];
#pragma unroll
    for (int m = 0; m < 4; ++m)
#pragma unroll
      for (int n = 0; n < 4; ++n) acc[m][n] = MFMA16(af[m], bfr[n], acc[m][n]);
    if (++buf == 3) buf = 0;
  }
#undef STAGE

#pragma unroll
  for (int n = 0; n < 4; ++n) {
    int col = n0 + wc * 64 + n * 16 + l16;
    float bq = bias[col];
    int which = col >> 10;
    int h = col & 1023;
    int head = h >> 6, d = h & 63;
    if (which == 2) {
#pragma unroll
      for (int m = 0; m < 4; ++m) {
        int row = m0 + wr * 64 + m * 16 + lg * 4;
        int b = row >> 10, ii = row & 1023;
        u16x4 o;
#pragma unroll
        for (int r = 0; r < 4; ++r) o[r] = f2b(acc[m][n][r] + bq);
        *(u16x4*)&Vt[(size_t)(((b * 16 + head) << 6) + d) * 1024 + ii] = o;
      }
    } else {
      u16* dst = which == 0 ? Qo : Ko;
      float scale = which == 1 ? 0.125f : 1.0f;
#pragma unroll
      for (int m = 0; m < 4; ++m) {
#pragma unroll
        for (int r = 0; r < 4; ++r) {
          int row = m0 + wr * 64 + m * 16 + lg * 4 + r;
          int b = row >> 10, ii = row & 1023;
          dst[(size_t)(((b * 16 + head) << 10) + ii) * 64 + d] = f2b((acc[m][n][r] + bq) * scale);
        }
      }
    }
  }
}

// ---------------- out = AO @ Wo^T + bo (R10-exact, frozen) ----------------
__global__ __launch_bounds__(256) void gemm_out(const u16* __restrict__ A, const u16* __restrict__ Bw,
                                                const float* __restrict__ bias, float* __restrict__ Co) {
  __shared__ u16 As[3][4][128][8];
  __shared__ u16 Bs[3][4][128][8];
  const int orig = blockIdx.y * 8 + blockIdx.x;
  const int xcd = orig & 7, q = orig >> 3;
  const int mt = (xcd << 2) + (q >> 3);
  const int nt = q & 7;
  const int m0 = mt * 128, n0 = nt * 128;
  const int t = threadIdx.x, lane = t & 63, w = t >> 6;
  const int wr = w >> 1, wc = w & 1;
  const int l16 = lane & 15, lg = lane >> 4;
  f32x4 acc[4][4] = {};
  const int r0 = t & 127, g0 = t >> 7;
  const int g1 = g0 + 2;

#define STAGE(buf, k0) do { \
    GLDS(&A[(size_t)(m0 + r0) * 1024 + (k0) + g0 * 8], &As[buf][g0][r0][0]); \
    GLDS(&A[(size_t)(m0 + r0) * 1024 + (k0) + g1 * 8], &As[buf][g1][r0][0]); \
    GLDS(&Bw[(size_t)(n0 + r0) * 1024 + (k0) + g0 * 8], &Bs[buf][g0][r0][0]); \
    GLDS(&Bw[(size_t)(n0 + r0) * 1024 + (k0) + g1 * 8], &Bs[buf][g1][r0][0]); \
  } while (0)

  STAGE(0, 0);
  STAGE(1, 32);

  int buf = 0;
  for (int kt = 0; kt < 32; ++kt) {
    if (kt < 31) PIPE_WAIT(4); else PIPE_WAIT(0);
    if (kt < 30) {
      int nb = buf + 2; if (nb >= 3) nb -= 3;
      STAGE(nb, (kt + 2) * 32);
      __builtin_amdgcn_sched_barrier(0);
    }
    bf16x8 af[4], bfr[4];
#pragma unroll
    for (int m = 0; m < 4; ++m) af[m] = *(const bf16x8*)&As[buf][lg][wr * 64 + m * 16 + l16][0];
#pragma unroll
    for (int n = 0; n < 4; ++n) bfr[n] = *(const bf16x8*)&Bs[buf][lg][wc * 64 + n * 16 + l16][0];
#pragma unroll
    for (int m = 0; m < 4; ++m)
#pragma unroll
      for (int n = 0; n < 4; ++n) acc[m][n] = MFMA16(af[m], bfr[n], acc[m][n]);
    if (++buf == 3) buf = 0;
  }
#undef STAGE

#pragma unroll
  for (int n = 0; n < 4; ++n) {
    int col = n0 + wc * 64 + n * 16 + l16;
    float bq = bias[col];
#pragma unroll
    for (int m = 0; m < 4; ++m) {
#pragma unroll
      for (int r = 0; r < 4; ++r) {
        int row = m0 + wr * 64 + m * 16 + lg * 4 + r;
        Co[(size_t)row * 1024 + col] = acc[m][n][r] + bq;
      }
    }
  }
}

// ---------------- fused causal attention, QBLK=128 ----------------
// grid (64 bn, 8), qt via balance LUT; block covers rows [i0, i0+128).
// 4 waves x 32 rows (2 strips of 16). K/V fragment reads shared across strips.
// F: 192-row ring window (phys(m) = (m - i0 + 63) mod 192), 64 new rows/iter.
__global__ __launch_bounds__(256) void attn_kernel(const u16* __restrict__ Qg, const u16* __restrict__ Kg,
                                                   const u16* __restrict__ Vtg, const u16* __restrict__ Fg,
                                                   u16* __restrict__ AO) {
  __shared__ u16 Kl[4096];          // [j][d] swz, 8 KB
  __shared__ u16 Vl[4096];          // [d][j] swz, 8 KB
  __shared__ u16 Fl[12288];         // 192-row ring [phys][d] swz, 24 KB
  __shared__ u16 BP[4][2048];       // per-wave 32x64: band gathered, then P swz; 16 KB

  const int bn = blockIdx.x;
  const int b = bn >> 4, n = bn & 15;
  const int QTLUT[8] = {7, 0, 6, 1, 5, 2, 4, 3};   // pair heavy+light per CU
  const int qt = QTLUT[blockIdx.y];
  const int i0 = qt * 128;
  const int nt = 2 * qt + 2;
  const int t = threadIdx.x, lane = t & 63, w = t >> 6;
  const int l16 = lane & 15, lg = lane >> 4;

  const int rr0 = t >> 3, cc0 = t & 7;            // rows 0..31
  const int rr1 = (t + 256) >> 3, cc1 = t & 7;    // rows 32..63

  // Q strip fragments: strip sr rows [i0+32w+16sr, +16)
  bf16x8 qf[2][2];
#pragma unroll
  for (int sr = 0; sr < 2; ++sr) {
    const u16* qp = &Qg[(size_t)((bn << 10) + i0 + 32 * w + 16 * sr + l16) * 64 + lg * 8];
    qf[sr][0] = *(const bf16x8*)qp;
    qf[sr][1] = *(const bf16x8*)(qp + 32);
  }

  // ---- prologue: stage full 192-row F window: m = i0 - 63 + prow ----
#pragma unroll
  for (int s = 0; s < 6; ++s) {
    int ch = t + 256 * s;
    int prow = ch >> 3, c = ch & 7;
    int m = i0 - 63 + prow;
    m = m < 0 ? 0 : (m > 1023 ? 1023 : m);
    u16x8 v = *(const u16x8*)&Fg[(size_t)((n << 10) + m) * 64 + c * 8];
    *(u16x8*)&Fl[prow * 64 + (((c ^ (prow & 7)) & 7) << 3)] = v;
  }

  float mrun[2][4], lsum[2][4];
  f32x4 ao[2][4] = {};
#pragma unroll
  for (int sr = 0; sr < 2; ++sr)
#pragma unroll
    for (int r = 0; r < 4; ++r) { mrun[sr][r] = -3.0e38f; lsum[sr][r] = 0.0f; }

  u16x8 rk0, rk1, rv0, rv1, rf0, rf1;

#define LOAD_KV(jt_) do { \
    int j0_ = (jt_) * 64; \
    rk0 = *(const u16x8*)&Kg[(size_t)((bn << 10) + j0_ + rr0) * 64 + cc0 * 8]; \
    rk1 = *(const u16x8*)&Kg[(size_t)((bn << 10) + j0_ + rr1) * 64 + cc1 * 8]; \
    rv0 = *(const u16x8*)&Vtg[(size_t)((bn << 6) + rr0) * 1024 + j0_ + cc0 * 8]; \
    rv1 = *(const u16x8*)&Vtg[(size_t)((bn << 6) + rr1) * 1024 + j0_ + cc1 * 8]; \
  } while (0)

#define LOAD_F(jt_) do { \
    int mb_ = i0 - 64 * (jt_) - 63; \
    int m0_ = mb_ + rr0; m0_ = m0_ < 0 ? 0 : (m0_ > 1023 ? 1023 : m0_); \
    int m1_ = mb_ + rr1; m1_ = m1_ < 0 ? 0 : (m1_ > 1023 ? 1023 : m1_); \
    rf0 = *(const u16x8*)&Fg[(size_t)((n << 10) + m0_) * 64 + cc0 * 8]; \
    rf1 = *(const u16x8*)&Fg[(size_t)((n << 10) + m1_) * 64 + cc1 * 8]; \
  } while (0)

  LOAD_KV(0);

  for (int jt = 0; jt < nt; ++jt) {
    const int j0 = jt * 64;

    // ---- write staged K/V (+ new F rows for jt>=1) ----
    *(u16x8*)&Kl[rr0 * 64 + (((cc0 ^ (rr0 & 7)) & 7) << 3)] = rk0;
    *(u16x8*)&Kl[rr1 * 64 + (((cc1 ^ (rr1 & 7)) & 7) << 3)] = rk1;
    *(u16x8*)&Vl[rr0 * 64 + (((cc0 ^ (rr0 & 7)) & 7) << 3)] = rv0;
    *(u16x8*)&Vl[rr1 * 64 + (((cc1 ^ (rr1 & 7)) & 7) << 3)] = rv1;
    if (jt >= 1) {
      int fb = 64 * ((3 - (jt % 3)) % 3);
      *(u16x8*)&Fl[(fb + rr0) * 64 + (((cc0 ^ (rr0 & 7)) & 7) << 3)] = rf0;
      *(u16x8*)&Fl[(fb + rr1) * 64 + (((cc1 ^ (rr1 & 7)) & 7) << 3)] = rf1;
    }
    TOP_BARRIER();

    if (jt + 1 < nt) { LOAD_KV(jt + 1); LOAD_F(jt + 1); }   // in flight across barriers

    // ---- QK^T: K fragment shared across strips ----
    __builtin_amdgcn_s_setprio(1);
    f32x4 sc[2][4] = {};
#pragma unroll
    for (int kk = 0; kk < 2; ++kk)
#pragma unroll
      for (int nn = 0; nn < 4; ++nn) {
        int jr = nn * 16 + l16;
        bf16x8 kb = *(const bf16x8*)&Kl[jr * 64 + ((((lg + 4 * kk) ^ (jr & 7)) & 7) << 3)];
        sc[0][nn] = MFMA16(qf[0][kk], kb, sc[0][nn]);
        sc[1][nn] = MFMA16(qf[1][kk], kb, sc[1][nn]);
      }
    __builtin_amdgcn_s_setprio(0);

    // ---- band per strip: window [Ibase-j0-63, +80), 5 tiles; scatter gathered ----
#pragma unroll
    for (int sr = 0; sr < 2; ++sr) {
      __builtin_amdgcn_s_setprio(1);
      f32x4 bb[5] = {};
#pragma unroll
      for (int kk = 0; kk < 2; ++kk)
#pragma unroll
        for (int ct = 0; ct < 5; ++ct) {
          int base_s = (32 * w + 16 * sr + 16 * ct + 1536 - 64 * jt) % 192;
          int prow = base_s + l16;
          bf16x8 fb = *(const bf16x8*)&Fl[prow * 64 + ((((lg + 4 * kk) ^ (prow & 7)) & 7) << 3)];
          bb[ct] = MFMA16(qf[sr][kk], fb, bb[ct]);
        }
      __builtin_amdgcn_s_setprio(0);
#pragma unroll
      for (int ct = 0; ct < 5; ++ct)
#pragma unroll
        for (int r = 0; r < 4; ++r) {
          int ils = lg * 4 + r;
          int jl = ils + 63 - (ct * 16 + l16);
          if ((unsigned)jl < 64u)
            BP[w][(sr * 16 + ils) * 64 + ((jl & 15) << 2) + (jl >> 4)] = f2b(bb[ct][r]);
        }
    }
    WAVE_LDS_FENCE();   // band scatter visible (BP wave-private)

    // ---- softmax both strips; wave-level defer ----
    float pv[2][4][4];
    float lmax[2][4];
#pragma unroll
    for (int sr = 0; sr < 2; ++sr)
#pragma unroll
      for (int r = 0; r < 4; ++r) {
        int il = sr * 16 + lg * 4 + r;
        int ig = i0 + 32 * w + 16 * sr + lg * 4 + r;
        u16x4 gv = *(const u16x4*)&BP[w][il * 64 + (l16 << 2)];
        float m4 = -3.0e38f;
#pragma unroll
        for (int nn = 0; nn < 4; ++nn) {
          int jg = j0 + nn * 16 + l16;
          float s = sc[sr][nn][r] + b2f(gv[nn]);
          if (jg > ig) s = -1.0e30f;   // causal (always valid check)
          pv[sr][nn][r] = s;
          m4 = fmaxf(m4, s);
        }
        lmax[sr][r] = m4;
      }
    bool ok = true;
#pragma unroll
    for (int sr = 0; sr < 2; ++sr)
#pragma unroll
      for (int r = 0; r < 4; ++r) ok = ok && (lmax[sr][r] <= mrun[sr][r] + 8.0f);
    if (__all(ok)) {
#pragma unroll
      for (int sr = 0; sr < 2; ++sr)
#pragma unroll
        for (int r = 0; r < 4; ++r) {
          float rs = 0.0f;
#pragma unroll
          for (int nn = 0; nn < 4; ++nn) {
            pv[sr][nn][r] = __expf(pv[sr][nn][r] - mrun[sr][r]);
            rs += pv[sr][nn][r];
          }
          lsum[sr][r] += rs;
        }
    } else {
#pragma unroll
      for (int sr = 0; sr < 2; ++sr)
#pragma unroll
        for (int r = 0; r < 4; ++r) {
          float mx = lmax[sr][r];
#pragma unroll
          for (int off = 1; off < 16; off <<= 1) mx = fmaxf(mx, __shfl_xor(mx, off));
          float mnew = fmaxf(mrun[sr][r], mx);
          float scl = __expf(mrun[sr][r] - mnew);
          float rs = 0.0f;
#pragma unroll
          for (int nn = 0; nn < 4; ++nn) {
            pv[sr][nn][r] = __expf(pv[sr][nn][r] - mnew);
            rs += pv[sr][nn][r];
          }
          lsum[sr][r] = lsum[sr][r] * scl + rs;
          mrun[sr][r] = mnew;
#pragma unroll
          for (int nd = 0; nd < 4; ++nd) ao[sr][nd][r] *= scl;
        }
    }

    // ---- P -> BP (A-operand swz layout), PV with V fragment shared ----
#pragma unroll
    for (int sr = 0; sr < 2; ++sr)
#pragma unroll
      for (int nn = 0; nn < 4; ++nn)
#pragma unroll
        for (int r = 0; r < 4; ++r) {
          int i = sr * 16 + lg * 4 + r, j = nn * 16 + l16;
          BP[w][i * 64 + ((((j >> 3) ^ (i & 7)) & 7) << 3) + (j & 7)] = f2b(pv[sr][nn][r]);
        }
    WAVE_LDS_FENCE();
    __builtin_amdgcn_s_setprio(1);
#pragma unroll
    for (int kk = 0; kk < 2; ++kk) {
      bf16x8 pa0 = *(const bf16x8*)&BP[w][l16 * 64 + ((((lg + 4 * kk) ^ (l16 & 7)) & 7) << 3)];
      bf16x8 pa1 = *(const bf16x8*)&BP[w][(16 + l16) * 64 + ((((lg + 4 * kk) ^ (l16 & 7)) & 7) << 3)];
#pragma unroll
      for (int nd = 0; nd < 4; ++nd) {
        int dr = nd * 16 + l16;
        bf16x8 vb = *(const bf16x8*)&Vl[dr * 64 + ((((lg + 4 * kk) ^ (dr & 7)) & 7) << 3)];
        ao[0][nd] = MFMA16(pa0, vb, ao[0][nd]);
        ao[1][nd] = MFMA16(pa1, vb, ao[1][nd]);
      }
    }
    __builtin_amdgcn_s_setprio(0);
    RAW_BARRIER();   // protect Kl/Vl/Fl (no vmcnt drain; prefetch survives)
  }

  // ---- finalize row sums, normalize + write ----
#pragma unroll
  for (int sr = 0; sr < 2; ++sr)
#pragma unroll
    for (int r = 0; r < 4; ++r)
#pragma unroll
      for (int off = 1; off < 16; off <<= 1) lsum[sr][r] += __shfl_xor(lsum[sr][r], off);

#pragma unroll
  for (int sr = 0; sr < 2; ++sr)
#pragma unroll
    for (int nd = 0; nd < 4; ++nd)
#pragma unroll
      for (int r = 0; r < 4; ++r) {
        int i = i0 + 32 * w + 16 * sr + lg * 4 + r;
        int d = nd * 16 + l16;
        float v = ao[sr][nd][r] / lsum[sr][r];
        AO[(size_t)((b << 10) + i) * 1024 + n * 64 + d] = f2b(v);
      }
#undef LOAD_KV
#undef LOAD_F
}

// ---------------- launch ----------------
extern "C" void kernel_launch(void* const* d_in, const int* in_sizes, int n_in,
                              void* d_out, int out_size, void* d_ws, size_t ws_size,
                              hipStream_t stream) {
  (void)in_sizes; (void)n_in; (void)out_size; (void)ws_size;
  const float* x    = (const float*)d_in[0];
  // d_in[1] = mask: always causal triu(k=1) -> analytic
  const float* Wqkv = (const float*)d_in[2];
  const float* bqkv = (const float*)d_in[3];
  const float* Wo   = (const float*)d_in[4];
  const float* bo   = (const float*)d_in[5];
  const float* Er   = (const float*)d_in[6];
  float* out = (float*)d_out;

  char* p = (char*)d_ws;
  u16* xb    = (u16*)p; p += (size_t)4096 * 1024 * 2;
  u16* wqkvb = (u16*)p; p += (size_t)3072 * 1024 * 2;
  u16* wob   = (u16*)p; p += (size_t)1024 * 1024 * 2;
  u16* Fb    = (u16*)p; p += (size_t)16 * 1024 * 64 * 2;
  u16* Qb    = (u16*)p; p += (size_t)64 * 1024 * 64 * 2;
  u16* Kb    = (u16*)p; p += (size_t)64 * 1024 * 64 * 2;
  u16* Vtb   = (u16*)p; p += (size_t)64 * 1024 * 64 * 2;   // V^T (bn, d, i)
  u16* AO    = (u16*)p; p += (size_t)4096 * 1024 * 2;

  cvt_all<<<8192, 256, 0, stream>>>(x, xb, Wqkv, wqkvb, Wo, wob);
  build_F<<<1024, 256, 0, stream>>>(Er, Fb);
  gemm_qkv<<<dim3(24, 32), 256, 0, stream>>>(xb, wqkvb, bqkv, Qb, Kb, Vtb);
  attn_kernel<<<dim3(64, 8), 256, 0, stream>>>(Qb, Kb, Vtb, Fb, AO);
  gemm_out<<<dim3(8, 32), 256, 0, stream>>>(AO, wob, bo, out);
}

// Round 15
// 146.494 us; speedup vs baseline: 1.2919x; 1.2919x over previous
//
#include <hip/hip_runtime.h>

typedef unsigned short u16;
typedef __bf16 bf16x8 __attribute__((ext_vector_type(8)));
typedef unsigned short u16x8 __attribute__((ext_vector_type(8)));
typedef unsigned short u16x4 __attribute__((ext_vector_type(4)));
typedef float f32x4 __attribute__((ext_vector_type(4)));

#define MFMA16(a, b, c) __builtin_amdgcn_mfma_f32_16x16x32_bf16((a), (b), (c), 0, 0, 0)

#define WAVE_LDS_FENCE() do { \
  asm volatile("s_waitcnt lgkmcnt(0)" ::: "memory"); \
  __builtin_amdgcn_sched_barrier(0); \
} while (0)

#define RAW_BARRIER() do { \
  __builtin_amdgcn_sched_barrier(0); \
  __builtin_amdgcn_s_barrier(); \
  __builtin_amdgcn_sched_barrier(0); \
} while (0)

#define TOP_BARRIER() do { \
  asm volatile("s_waitcnt lgkmcnt(0)" ::: "memory"); \
  RAW_BARRIER(); \
} while (0)

#define PIPE_WAIT(N) do { \
  asm volatile("s_waitcnt vmcnt(" #N ")" ::: "memory"); \
  __builtin_amdgcn_sched_barrier(0); \
  __builtin_amdgcn_s_barrier(); \
  __builtin_amdgcn_sched_barrier(0); \
} while (0)

#define GLDS(gp, lp) __builtin_amdgcn_global_load_lds( \
    (const __attribute__((address_space(1))) unsigned int*)(gp), \
    (__attribute__((address_space(3))) unsigned int*)(lp), 16, 0, 0)

__device__ __forceinline__ u16 f2b(float f) {
  unsigned u = __float_as_uint(f);
  u += 0x7fffu + ((u >> 16) & 1u);   // RNE; inputs finite
  return (u16)(u >> 16);
}
__device__ __forceinline__ float b2f(u16 h) {
  return __uint_as_float(((unsigned)h) << 16);
}

// ---------------- fused converts (x, Wqkv, Wo) + F table build ----------------
// F[n][m][d] = Er[n][(2048 - m) % 2048][d]  (chunks >= 2097152)
__global__ void cvt_all(const float* __restrict__ x, u16* __restrict__ xb,
                        const float* __restrict__ w1, u16* __restrict__ w1b,
                        const float* __restrict__ w2, u16* __restrict__ w2b,
                        const float* __restrict__ Er, u16* __restrict__ Fb) {
  int i = blockIdx.x * blockDim.x + threadIdx.x;   // float4 chunk id, < 2359296
  const float* s; u16* d; size_t soff, doff;
  if (i < 1048576)      { s = x;  d = xb;  soff = doff = (size_t)i * 4; }
  else if (i < 1835008) { s = w1; d = w1b; soff = doff = (size_t)(i - 1048576) * 4; }
  else if (i < 2097152) { s = w2; d = w2b; soff = doff = (size_t)(i - 1835008) * 4; }
  else {
    int base = (i - 2097152) * 4;
    int dd = base & 63;
    int m = (base >> 6) & 1023;
    int n = base >> 16;
    int sm = (2048 - m) & 2047;
    s = Er; d = Fb;
    soff = (size_t)(n * 2048 + sm) * 64 + dd;
    doff = (size_t)base;
  }
  float4 v = *(const float4*)(s + soff);
  *(ushort4*)(d + doff) = make_ushort4(f2b(v.x), f2b(v.y), f2b(v.z), f2b(v.w));
}

// ---------------- QKV GEMM: 3-buf counted-vmcnt pipeline, BK=32 (R10-exact, frozen) ----------------
__global__ __launch_bounds__(256) void gemm_qkv(const u16* __restrict__ A, const u16* __restrict__ Bw,
                                                const float* __restrict__ bias,
                                                u16* __restrict__ Qo, u16* __restrict__ Ko,
                                                u16* __restrict__ Vt) {
  __shared__ u16 As[3][4][128][8];
  __shared__ u16 Bs[3][4][128][8];
  const int orig = blockIdx.y * 24 + blockIdx.x;   // gridDim = (24, 32)
  const int xcd = orig & 7, q = orig >> 3;         // 96 blocks/XCD
  const int mt = ((xcd >> 1) << 3) + q / 12;
  const int nt = (xcd & 1) * 12 + q % 12;
  const int m0 = mt * 128, n0 = nt * 128;
  const int t = threadIdx.x, lane = t & 63, w = t >> 6;
  const int wr = w >> 1, wc = w & 1;
  const int l16 = lane & 15, lg = lane >> 4;
  f32x4 acc[4][4] = {};
  const int r0 = t & 127, g0 = t >> 7;
  const int g1 = g0 + 2;

#define STAGE(buf, k0) do { \
    GLDS(&A[(size_t)(m0 + r0) * 1024 + (k0) + g0 * 8], &As[buf][g0][r0][0]); \
    GLDS(&A[(size_t)(m0 + r0) * 1024 + (k0) + g1 * 8], &As[buf][g1][r0][0]); \
    GLDS(&Bw[(size_t)(n0 + r0) * 1024 + (k0) + g0 * 8], &Bs[buf][g0][r0][0]); \
    GLDS(&Bw[(size_t)(n0 + r0) * 1024 + (k0) + g1 * 8], &Bs[buf][g1][r0][0]); \
  } while (0)

  STAGE(0, 0);
  STAGE(1, 32);

  int buf = 0;
  for (int kt = 0; kt < 32; ++kt) {
    if (kt < 31) PIPE_WAIT(4); else PIPE_WAIT(0);
    if (kt < 30) {
      int nb = buf + 2; if (nb >= 3) nb -= 3;
      STAGE(nb, (kt + 2) * 32);
      __builtin_amdgcn_sched_barrier(0);
    }
    bf16x8 af[4], bfr[4];
#pragma unroll
    for (int m = 0; m < 4; ++m) af[m] = *(const bf16x8*)&As[buf][lg][wr * 64 + m * 16 + l16][0];
#pragma unroll
    for (int n = 0; n < 4; ++n) bfr[n] = *(const bf16x8*)&Bs[buf][lg][wc * 64 + n * 16 + l16][0];
#pragma unroll
    for (int m = 0; m < 4; ++m)
#pragma unroll
      for (int n = 0; n < 4; ++n) acc[m][n] = MFMA16(af[m], bfr[n], acc[m][n]);
    if (++buf == 3) buf = 0;
  }
#undef STAGE

#pragma unroll
  for (int n = 0; n < 4; ++n) {
    int col = n0 + wc * 64 + n * 16 + l16;
    float bq = bias[col];
    int which = col >> 10;
    int h = col & 1023;
    int head = h >> 6, d = h & 63;
    if (which == 2) {
#pragma unroll
      for (int m = 0; m < 4; ++m) {
        int row = m0 + wr * 64 + m * 16 + lg * 4;
        int b = row >> 10, ii = row & 1023;
        u16x4 o;
#pragma unroll
        for (int r = 0; r < 4; ++r) o[r] = f2b(acc[m][n][r] + bq);
        *(u16x4*)&Vt[(size_t)(((b * 16 + head) << 6) + d) * 1024 + ii] = o;
      }
    } else {
      u16* dst = which == 0 ? Qo : Ko;
      float scale = which == 1 ? 0.125f : 1.0f;
#pragma unroll
      for (int m = 0; m < 4; ++m) {
#pragma unroll
        for (int r = 0; r < 4; ++r) {
          int row = m0 + wr * 64 + m * 16 + lg * 4 + r;
          int b = row >> 10, ii = row & 1023;
          dst[(size_t)(((b * 16 + head) << 10) + ii) * 64 + d] = f2b((acc[m][n][r] + bq) * scale);
        }
      }
    }
  }
}

// ---------------- out = AO @ Wo^T + bo (R10-exact, frozen) ----------------
__global__ __launch_bounds__(256) void gemm_out(const u16* __restrict__ A, const u16* __restrict__ Bw,
                                                const float* __restrict__ bias, float* __restrict__ Co) {
  __shared__ u16 As[3][4][128][8];
  __shared__ u16 Bs[3][4][128][8];
  const int orig = blockIdx.y * 8 + blockIdx.x;
  const int xcd = orig & 7, q = orig >> 3;
  const int mt = (xcd << 2) + (q >> 3);
  const int nt = q & 7;
  const int m0 = mt * 128, n0 = nt * 128;
  const int t = threadIdx.x, lane = t & 63, w = t >> 6;
  const int wr = w >> 1, wc = w & 1;
  const int l16 = lane & 15, lg = lane >> 4;
  f32x4 acc[4][4] = {};
  const int r0 = t & 127, g0 = t >> 7;
  const int g1 = g0 + 2;

#define STAGE(buf, k0) do { \
    GLDS(&A[(size_t)(m0 + r0) * 1024 + (k0) + g0 * 8], &As[buf][g0][r0][0]); \
    GLDS(&A[(size_t)(m0 + r0) * 1024 + (k0) + g1 * 8], &As[buf][g1][r0][0]); \
    GLDS(&Bw[(size_t)(n0 + r0) * 1024 + (k0) + g0 * 8], &Bs[buf][g0][r0][0]); \
    GLDS(&Bw[(size_t)(n0 + r0) * 1024 + (k0) + g1 * 8], &Bs[buf][g1][r0][0]); \
  } while (0)

  STAGE(0, 0);
  STAGE(1, 32);

  int buf = 0;
  for (int kt = 0; kt < 32; ++kt) {
    if (kt < 31) PIPE_WAIT(4); else PIPE_WAIT(0);
    if (kt < 30) {
      int nb = buf + 2; if (nb >= 3) nb -= 3;
      STAGE(nb, (kt + 2) * 32);
      __builtin_amdgcn_sched_barrier(0);
    }
    bf16x8 af[4], bfr[4];
#pragma unroll
    for (int m = 0; m < 4; ++m) af[m] = *(const bf16x8*)&As[buf][lg][wr * 64 + m * 16 + l16][0];
#pragma unroll
    for (int n = 0; n < 4; ++n) bfr[n] = *(const bf16x8*)&Bs[buf][lg][wc * 64 + n * 16 + l16][0];
#pragma unroll
    for (int m = 0; m < 4; ++m)
#pragma unroll
      for (int n = 0; n < 4; ++n) acc[m][n] = MFMA16(af[m], bfr[n], acc[m][n]);
    if (++buf == 3) buf = 0;
  }
#undef STAGE

#pragma unroll
  for (int n = 0; n < 4; ++n) {
    int col = n0 + wc * 64 + n * 16 + l16;
    float bq = bias[col];
#pragma unroll
    for (int m = 0; m < 4; ++m) {
#pragma unroll
      for (int r = 0; r < 4; ++r) {
        int row = m0 + wr * 64 + m * 16 + lg * 4 + r;
        Co[(size_t)row * 1024 + col] = acc[m][n][r] + bq;
      }
    }
  }
}

// ---------------- fused causal attention with relative bias (R13-exact, best known) ----------------
__global__ __launch_bounds__(256) void attn_kernel(const u16* __restrict__ Qg, const u16* __restrict__ Kg,
                                                   const u16* __restrict__ Vtg, const u16* __restrict__ Fg,
                                                   u16* __restrict__ AO) {
  __shared__ u16 Kl[4096];          // [j][d] swz
  __shared__ u16 Vl[4096];          // [d][j] swz
  __shared__ u16 Fl[8192];          // [t^par][d] swz, 128 rows, half-ring
  __shared__ u16 BP[4][1024];       // per-wave union: band gather layout, then P

  const int bn = blockIdx.x;
  const int b = bn >> 4, n = bn & 15;
  const int qt = 15 - (int)blockIdx.y;       // heavy tiles first
  const int i0 = qt * 64;
  const int t = threadIdx.x, lane = t & 63, w = t >> 6;
  const int l16 = lane & 15, lg = lane >> 4;

  const int rr0 = t >> 3, cc0 = t & 7;            // rows 0..31
  const int rr1 = (t + 256) >> 3, cc1 = t & 7;    // rows 32..63

  bf16x8 qf[2];
  {
    const u16* qp = &Qg[(size_t)((bn << 10) + i0 + (w << 4) + l16) * 64 + lg * 8];
    qf[0] = *(const bf16x8*)qp;
    qf[1] = *(const bf16x8*)(qp + 32);
  }

  // ---- prologue: stage F high half (rows 64..127 of window 0, par=0) ----
  {
    int mb0 = i0 - 63;
    int h0 = 64 + rr0, h1 = 64 + rr1;
    int gm0 = mb0 + h0; gm0 = gm0 < 0 ? 0 : (gm0 > 1023 ? 1023 : gm0);
    int gm1 = mb0 + h1; gm1 = gm1 < 0 ? 0 : (gm1 > 1023 ? 1023 : gm1);
    u16x8 a = *(const u16x8*)&Fg[(size_t)((n << 10) + gm0) * 64 + cc0 * 8];
    u16x8 c = *(const u16x8*)&Fg[(size_t)((n << 10) + gm1) * 64 + cc1 * 8];
    *(u16x8*)&Fl[h0 * 64 + (((cc0 ^ (h0 & 7)) & 7) << 3)] = a;
    *(u16x8*)&Fl[h1 * 64 + (((cc1 ^ (h1 & 7)) & 7) << 3)] = c;
  }

  float mrun[4], lsum[4];
  f32x4 ao[4] = {};
#pragma unroll
  for (int r = 0; r < 4; ++r) { mrun[r] = -3.0e38f; lsum[r] = 0.0f; }

  u16x8 rk0, rk1, rv0, rv1, rf0, rf1;

#define LOAD_STAGE(jt_) do { \
    int j0_ = (jt_) * 64, mb_ = i0 - j0_ - 63; \
    rk0 = *(const u16x8*)&Kg[(size_t)((bn << 10) + j0_ + rr0) * 64 + cc0 * 8]; \
    rk1 = *(const u16x8*)&Kg[(size_t)((bn << 10) + j0_ + rr1) * 64 + cc1 * 8]; \
    rv0 = *(const u16x8*)&Vtg[(size_t)((bn << 6) + rr0) * 1024 + j0_ + cc0 * 8]; \
    rv1 = *(const u16x8*)&Vtg[(size_t)((bn << 6) + rr1) * 1024 + j0_ + cc1 * 8]; \
    int m0_ = mb_ + rr0; m0_ = m0_ < 0 ? 0 : (m0_ > 1023 ? 1023 : m0_); \
    int m1_ = mb_ + rr1; m1_ = m1_ < 0 ? 0 : (m1_ > 1023 ? 1023 : m1_); \
    rf0 = *(const u16x8*)&Fg[(size_t)((n << 10) + m0_) * 64 + cc0 * 8]; \
    rf1 = *(const u16x8*)&Fg[(size_t)((n << 10) + m1_) * 64 + cc1 * 8]; \
  } while (0)

  LOAD_STAGE(0);

  for (int jt = 0; jt <= qt; ++jt) {
    const bool diag = (jt == qt);
    const int ph = (jt & 1) << 6;      // F half-ring parity

    *(u16x8*)&Kl[rr0 * 64 + (((cc0 ^ (rr0 & 7)) & 7) << 3)] = rk0;
    *(u16x8*)&Kl[rr1 * 64 + (((cc1 ^ (rr1 & 7)) & 7) << 3)] = rk1;
    *(u16x8*)&Vl[rr0 * 64 + (((cc0 ^ (rr0 & 7)) & 7) << 3)] = rv0;
    *(u16x8*)&Vl[rr1 * 64 + (((cc1 ^ (rr1 & 7)) & 7) << 3)] = rv1;
    *(u16x8*)&Fl[(rr0 ^ ph) * 64 + (((cc0 ^ (rr0 & 7)) & 7) << 3)] = rf0;
    *(u16x8*)&Fl[(rr1 ^ ph) * 64 + (((cc1 ^ (rr1 & 7)) & 7) << 3)] = rf1;
    TOP_BARRIER();                     // lgkm drain + raw barrier (no vmcnt drain)

    if (jt < qt) LOAD_STAGE(jt + 1);   // in flight across the bottom barrier

    // ---- QK^T + band (MFMA cluster, setprio) ----
    __builtin_amdgcn_s_setprio(1);
    f32x4 sc[4] = {};
#pragma unroll
    for (int kk = 0; kk < 2; ++kk)
#pragma unroll
      for (int nn = 0; nn < 4; ++nn) {
        int jr = nn * 16 + l16;
        bf16x8 kb = *(const bf16x8*)&Kl[jr * 64 + ((((lg + 4 * kk) ^ (jr & 7)) & 7) << 3)];
        sc[nn] = MFMA16(qf[kk], kb, sc[nn]);
      }
    f32x4 bb[5] = {};
#pragma unroll
    for (int kk = 0; kk < 2; ++kk)
#pragma unroll
      for (int ct = 0; ct < 5; ++ct) {
        int trow = (w << 4) + ct * 16 + l16;
        bf16x8 fb = *(const bf16x8*)&Fl[(trow ^ ph) * 64 + ((((lg + 4 * kk) ^ (trow & 7)) & 7) << 3)];
        bb[ct] = MFMA16(qf[kk], fb, bb[ct]);
      }
    __builtin_amdgcn_s_setprio(0);

    // ---- scatter band to gathered layout ----
#pragma unroll
    for (int ct = 0; ct < 5; ++ct)
#pragma unroll
      for (int r = 0; r < 4; ++r) {
        int il = lg * 4 + r;
        int jl = il + 63 - (ct * 16 + l16);
        if ((unsigned)jl < 64u)
          BP[w][il * 64 + ((jl & 15) << 2) + (jl >> 4)] = f2b(bb[ct][r]);
      }
    WAVE_LDS_FENCE();

    // ---- assemble S; lane-local max; wave-level defer check ----
    float pv[4][4];
    float lmax[4];
#pragma unroll
    for (int r = 0; r < 4; ++r) {
      int il = lg * 4 + r;
      u16x4 gv = *(const u16x4*)&BP[w][il * 64 + (l16 << 2)];
      float m4 = -3.0e38f;
#pragma unroll
      for (int nn = 0; nn < 4; ++nn) {
        int jl = nn * 16 + l16;
        float s = sc[nn][r] + b2f(gv[nn]);
        if (diag && jl > (w << 4) + il) s = -1.0e30f;   // j > i
        pv[nn][r] = s;
        m4 = fmaxf(m4, s);
      }
      lmax[r] = m4;
    }
    bool ok = (lmax[0] <= mrun[0] + 8.0f) && (lmax[1] <= mrun[1] + 8.0f) &&
              (lmax[2] <= mrun[2] + 8.0f) && (lmax[3] <= mrun[3] + 8.0f);
    if (__all(ok)) {
#pragma unroll
      for (int r = 0; r < 4; ++r) {
        float rs = 0.0f;
#pragma unroll
        for (int nn = 0; nn < 4; ++nn) {
          pv[nn][r] = __expf(pv[nn][r] - mrun[r]);
          rs += pv[nn][r];
        }
        lsum[r] += rs;
      }
    } else {
#pragma unroll
      for (int r = 0; r < 4; ++r) {
        float mx = lmax[r];
#pragma unroll
        for (int off = 1; off < 16; off <<= 1) mx = fmaxf(mx, __shfl_xor(mx, off));
        float mnew = fmaxf(mrun[r], mx);
        float scl = __expf(mrun[r] - mnew);
        float rs = 0.0f;
#pragma unroll
        for (int nn = 0; nn < 4; ++nn) {
          pv[nn][r] = __expf(pv[nn][r] - mnew);
          rs += pv[nn][r];
        }
        lsum[r] = lsum[r] * scl + rs;
        mrun[r] = mnew;
#pragma unroll
        for (int nd = 0; nd < 4; ++nd) ao[nd][r] *= scl;
      }
    }

    // ---- P -> BP (swz layout), PV ----
#pragma unroll
    for (int nn = 0; nn < 4; ++nn)
#pragma unroll
      for (int r = 0; r < 4; ++r) {
        int i = lg * 4 + r, j = nn * 16 + l16;
        BP[w][i * 64 + ((((j >> 3) ^ (i & 7)) & 7) << 3) + (j & 7)] = f2b(pv[nn][r]);
      }
    WAVE_LDS_FENCE();
    __builtin_amdgcn_s_setprio(1);
#pragma unroll
    for (int kk = 0; kk < 2; ++kk) {
      bf16x8 pa = *(const bf16x8*)&BP[w][l16 * 64 + ((((lg + 4 * kk) ^ (l16 & 7)) & 7) << 3)];
#pragma unroll
      for (int nd = 0; nd < 4; ++nd) {
        int dr = nd * 16 + l16;
        bf16x8 vb = *(const bf16x8*)&Vl[dr * 64 + ((((lg + 4 * kk) ^ (dr & 7)) & 7) << 3)];
        ao[nd] = MFMA16(pa, vb, ao[nd]);
      }
    }
    __builtin_amdgcn_s_setprio(0);
    RAW_BARRIER();   // protect Kl/Vl/Fl (no vmcnt drain; prefetch survives)
  }

  // ---- finalize row sums, normalize + write ----
#pragma unroll
  for (int r = 0; r < 4; ++r)
#pragma unroll
    for (int off = 1; off < 16; off <<= 1) lsum[r] += __shfl_xor(lsum[r], off);

#pragma unroll
  for (int nd = 0; nd < 4; ++nd)
#pragma unroll
    for (int r = 0; r < 4; ++r) {
      int i = i0 + (w << 4) + lg * 4 + r;
      int d = nd * 16 + l16;
      float v = ao[nd][r] / lsum[r];
      AO[(size_t)((b << 10) + i) * 1024 + n * 64 + d] = f2b(v);
    }
#undef LOAD_STAGE
}

// ---------------- launch ----------------
extern "C" void kernel_launch(void* const* d_in, const int* in_sizes, int n_in,
                              void* d_out, int out_size, void* d_ws, size_t ws_size,
                              hipStream_t stream) {
  (void)in_sizes; (void)n_in; (void)out_size; (void)ws_size;
  const float* x    = (const float*)d_in[0];
  // d_in[1] = mask: always causal triu(k=1) -> analytic
  const float* Wqkv = (const float*)d_in[2];
  const float* bqkv = (const float*)d_in[3];
  const float* Wo   = (const float*)d_in[4];
  const float* bo   = (const float*)d_in[5];
  const float* Er   = (const float*)d_in[6];
  float* out = (float*)d_out;

  char* p = (char*)d_ws;
  u16* xb    = (u16*)p; p += (size_t)4096 * 1024 * 2;
  u16* wqkvb = (u16*)p; p += (size_t)3072 * 1024 * 2;
  u16* wob   = (u16*)p; p += (size_t)1024 * 1024 * 2;
  u16* Fb    = (u16*)p; p += (size_t)16 * 1024 * 64 * 2;
  u16* Qb    = (u16*)p; p += (size_t)64 * 1024 * 64 * 2;
  u16* Kb    = (u16*)p; p += (size_t)64 * 1024 * 64 * 2;
  u16* Vtb   = (u16*)p; p += (size_t)64 * 1024 * 64 * 2;   // V^T (bn, d, i)
  u16* AO    = (u16*)p; p += (size_t)4096 * 1024 * 2;

  cvt_all<<<9216, 256, 0, stream>>>(x, xb, Wqkv, wqkvb, Wo, wob, Er, Fb);
  gemm_qkv<<<dim3(24, 32), 256, 0, stream>>>(xb, wqkvb, bqkv, Qb, Kb, Vtb);
  attn_kernel<<<dim3(64, 16), 256, 0, stream>>>(Qb, Kb, Vtb, Fb, AO);
  gemm_out<<<dim3(8, 32), 256, 0, stream>>>(AO, wob, bo, out);
}

// Round 16
// 146.314 us; speedup vs baseline: 1.2935x; 1.0012x over previous
//
#include <hip/hip_runtime.h>

typedef unsigned short u16;
typedef __bf16 bf16x8 __attribute__((ext_vector_type(8)));
typedef unsigned short u16x8 __attribute__((ext_vector_type(8)));
typedef unsigned short u16x4 __attribute__((ext_vector_type(4)));
typedef float f32x4 __attribute__((ext_vector_type(4)));

#define MFMA16(a, b, c) __builtin_amdgcn_mfma_f32_16x16x32_bf16((a), (b), (c), 0, 0, 0)

#define WAVE_LDS_FENCE() do { \
  asm volatile("s_waitcnt lgkmcnt(0)" ::: "memory"); \
  __builtin_amdgcn_sched_barrier(0); \
} while (0)

#define RAW_BARRIER() do { \
  __builtin_amdgcn_sched_barrier(0); \
  __builtin_amdgcn_s_barrier(); \
  __builtin_amdgcn_sched_barrier(0); \
} while (0)

#define TOP_BARRIER() do { \
  asm volatile("s_waitcnt lgkmcnt(0)" ::: "memory"); \
  RAW_BARRIER(); \
} while (0)

#define PIPE_WAIT(N) do { \
  asm volatile("s_waitcnt vmcnt(" #N ")" ::: "memory"); \
  __builtin_amdgcn_sched_barrier(0); \
  __builtin_amdgcn_s_barrier(); \
  __builtin_amdgcn_sched_barrier(0); \
} while (0)

#define GLDS(gp, lp) __builtin_amdgcn_global_load_lds( \
    (const __attribute__((address_space(1))) unsigned int*)(gp), \
    (__attribute__((address_space(3))) unsigned int*)(lp), 16, 0, 0)

__device__ __forceinline__ u16 f2b(float f) {
  unsigned u = __float_as_uint(f);
  u += 0x7fffu + ((u >> 16) & 1u);   // RNE; inputs finite
  return (u16)(u >> 16);
}
__device__ __forceinline__ float b2f(u16 h) {
  return __uint_as_float(((unsigned)h) << 16);
}

// ---------------- fused converts (x, Wqkv, Wo) + F table build ----------------
// F[n][m][d] = Er[n][(2048 - m) % 2048][d]  (chunks >= 2097152)
__global__ void cvt_all(const float* __restrict__ x, u16* __restrict__ xb,
                        const float* __restrict__ w1, u16* __restrict__ w1b,
                        const float* __restrict__ w2, u16* __restrict__ w2b,
                        const float* __restrict__ Er, u16* __restrict__ Fb) {
  int i = blockIdx.x * blockDim.x + threadIdx.x;   // float4 chunk id, < 2359296
  const float* s; u16* d; size_t soff, doff;
  if (i < 1048576)      { s = x;  d = xb;  soff = doff = (size_t)i * 4; }
  else if (i < 1835008) { s = w1; d = w1b; soff = doff = (size_t)(i - 1048576) * 4; }
  else if (i < 2097152) { s = w2; d = w2b; soff = doff = (size_t)(i - 1835008) * 4; }
  else {
    int base = (i - 2097152) * 4;
    int dd = base & 63;
    int m = (base >> 6) & 1023;
    int n = base >> 16;
    int sm = (2048 - m) & 2047;
    s = Er; d = Fb;
    soff = (size_t)(n * 2048 + sm) * 64 + dd;
    doff = (size_t)base;
  }
  float4 v = *(const float4*)(s + soff);
  *(ushort4*)(d + doff) = make_ushort4(f2b(v.x), f2b(v.y), f2b(v.z), f2b(v.w));
}

// ---------------- QKV GEMM: 3-buf counted-vmcnt pipeline, BK=32 (frozen optimum) ----------------
__global__ __launch_bounds__(256) void gemm_qkv(const u16* __restrict__ A, const u16* __restrict__ Bw,
                                                const float* __restrict__ bias,
                                                u16* __restrict__ Qo, u16* __restrict__ Ko,
                                                u16* __restrict__ Vt) {
  __shared__ u16 As[3][4][128][8];
  __shared__ u16 Bs[3][4][128][8];
  const int orig = blockIdx.y * 24 + blockIdx.x;   // gridDim = (24, 32)
  const int xcd = orig & 7, q = orig >> 3;         // 96 blocks/XCD
  const int mt = ((xcd >> 1) << 3) + q / 12;
  const int nt = (xcd & 1) * 12 + q % 12;
  const int m0 = mt * 128, n0 = nt * 128;
  const int t = threadIdx.x, lane = t & 63, w = t >> 6;
  const int wr = w >> 1, wc = w & 1;
  const int l16 = lane & 15, lg = lane >> 4;
  f32x4 acc[4][4] = {};
  const int r0 = t & 127, g0 = t >> 7;
  const int g1 = g0 + 2;

#define STAGE(buf, k0) do { \
    GLDS(&A[(size_t)(m0 + r0) * 1024 + (k0) + g0 * 8], &As[buf][g0][r0][0]); \
    GLDS(&A[(size_t)(m0 + r0) * 1024 + (k0) + g1 * 8], &As[buf][g1][r0][0]); \
    GLDS(&Bw[(size_t)(n0 + r0) * 1024 + (k0) + g0 * 8], &Bs[buf][g0][r0][0]); \
    GLDS(&Bw[(size_t)(n0 + r0) * 1024 + (k0) + g1 * 8], &Bs[buf][g1][r0][0]); \
  } while (0)

  STAGE(0, 0);
  STAGE(1, 32);

  int buf = 0;
  for (int kt = 0; kt < 32; ++kt) {
    if (kt < 31) PIPE_WAIT(4); else PIPE_WAIT(0);
    if (kt < 30) {
      int nb = buf + 2; if (nb >= 3) nb -= 3;
      STAGE(nb, (kt + 2) * 32);
      __builtin_amdgcn_sched_barrier(0);
    }
    bf16x8 af[4], bfr[4];
#pragma unroll
    for (int m = 0; m < 4; ++m) af[m] = *(const bf16x8*)&As[buf][lg][wr * 64 + m * 16 + l16][0];
#pragma unroll
    for (int n = 0; n < 4; ++n) bfr[n] = *(const bf16x8*)&Bs[buf][lg][wc * 64 + n * 16 + l16][0];
#pragma unroll
    for (int m = 0; m < 4; ++m)
#pragma unroll
      for (int n = 0; n < 4; ++n) acc[m][n] = MFMA16(af[m], bfr[n], acc[m][n]);
    if (++buf == 3) buf = 0;
  }
#undef STAGE

#pragma unroll
  for (int n = 0; n < 4; ++n) {
    int col = n0 + wc * 64 + n * 16 + l16;
    float bq = bias[col];
    int which = col >> 10;
    int h = col & 1023;
    int head = h >> 6, d = h & 63;
    if (which == 2) {
#pragma unroll
      for (int m = 0; m < 4; ++m) {
        int row = m0 + wr * 64 + m * 16 + lg * 4;
        int b = row >> 10, ii = row & 1023;
        u16x4 o;
#pragma unroll
        for (int r = 0; r < 4; ++r) o[r] = f2b(acc[m][n][r] + bq);
        *(u16x4*)&Vt[(size_t)(((b * 16 + head) << 6) + d) * 1024 + ii] = o;
      }
    } else {
      u16* dst = which == 0 ? Qo : Ko;
      float scale = which == 1 ? 0.125f : 1.0f;
#pragma unroll
      for (int m = 0; m < 4; ++m) {
#pragma unroll
        for (int r = 0; r < 4; ++r) {
          int row = m0 + wr * 64 + m * 16 + lg * 4 + r;
          int b = row >> 10, ii = row & 1023;
          dst[(size_t)(((b * 16 + head) << 10) + ii) * 64 + d] = f2b((acc[m][n][r] + bq) * scale);
        }
      }
    }
  }
}

// ---------------- out = AO @ Wo^T + bo (frozen optimum) ----------------
__global__ __launch_bounds__(256) void gemm_out(const u16* __restrict__ A, const u16* __restrict__ Bw,
                                                const float* __restrict__ bias, float* __restrict__ Co) {
  __shared__ u16 As[3][4][128][8];
  __shared__ u16 Bs[3][4][128][8];
  const int orig = blockIdx.y * 8 + blockIdx.x;
  const int xcd = orig & 7, q = orig >> 3;
  const int mt = (xcd << 2) + (q >> 3);
  const int nt = q & 7;
  const int m0 = mt * 128, n0 = nt * 128;
  const int t = threadIdx.x, lane = t & 63, w = t >> 6;
  const int wr = w >> 1, wc = w & 1;
  const int l16 = lane & 15, lg = lane >> 4;
  f32x4 acc[4][4] = {};
  const int r0 = t & 127, g0 = t >> 7;
  const int g1 = g0 + 2;

#define STAGE(buf, k0) do { \
    GLDS(&A[(size_t)(m0 + r0) * 1024 + (k0) + g0 * 8], &As[buf][g0][r0][0]); \
    GLDS(&A[(size_t)(m0 + r0) * 1024 + (k0) + g1 * 8], &As[buf][g1][r0][0]); \
    GLDS(&Bw[(size_t)(n0 + r0) * 1024 + (k0) + g0 * 8], &Bs[buf][g0][r0][0]); \
    GLDS(&Bw[(size_t)(n0 + r0) * 1024 + (k0) + g1 * 8], &Bs[buf][g1][r0][0]); \
  } while (0)

  STAGE(0, 0);
  STAGE(1, 32);

  int buf = 0;
  for (int kt = 0; kt < 32; ++kt) {
    if (kt < 31) PIPE_WAIT(4); else PIPE_WAIT(0);
    if (kt < 30) {
      int nb = buf + 2; if (nb >= 3) nb -= 3;
      STAGE(nb, (kt + 2) * 32);
      __builtin_amdgcn_sched_barrier(0);
    }
    bf16x8 af[4], bfr[4];
#pragma unroll
    for (int m = 0; m < 4; ++m) af[m] = *(const bf16x8*)&As[buf][lg][wr * 64 + m * 16 + l16][0];
#pragma unroll
    for (int n = 0; n < 4; ++n) bfr[n] = *(const bf16x8*)&Bs[buf][lg][wc * 64 + n * 16 + l16][0];
#pragma unroll
    for (int m = 0; m < 4; ++m)
#pragma unroll
      for (int n = 0; n < 4; ++n) acc[m][n] = MFMA16(af[m], bfr[n], acc[m][n]);
    if (++buf == 3) buf = 0;
  }
#undef STAGE

#pragma unroll
  for (int n = 0; n < 4; ++n) {
    int col = n0 + wc * 64 + n * 16 + l16;
    float bq = bias[col];
#pragma unroll
    for (int m = 0; m < 4; ++m) {
#pragma unroll
      for (int r = 0; r < 4; ++r) {
        int row = m0 + wr * 64 + m * 16 + lg * 4 + r;
        Co[(size_t)row * 1024 + col] = acc[m][n][r] + bq;
      }
    }
  }
}

// ---------------- fused causal attention with relative bias (frozen optimum) ----------------
__global__ __launch_bounds__(256) void attn_kernel(const u16* __restrict__ Qg, const u16* __restrict__ Kg,
                                                   const u16* __restrict__ Vtg, const u16* __restrict__ Fg,
                                                   u16* __restrict__ AO) {
  __shared__ u16 Kl[4096];          // [j][d] swz
  __shared__ u16 Vl[4096];          // [d][j] swz
  __shared__ u16 Fl[8192];          // [t^par][d] swz, 128 rows, half-ring
  __shared__ u16 BP[4][1024];       // per-wave union: band gather layout, then P

  const int bn = blockIdx.x;
  const int b = bn >> 4, n = bn & 15;
  const int qt = 15 - (int)blockIdx.y;       // heavy tiles first
  const int i0 = qt * 64;
  const int t = threadIdx.x, lane = t & 63, w = t >> 6;
  const int l16 = lane & 15, lg = lane >> 4;

  const int rr0 = t >> 3, cc0 = t & 7;            // rows 0..31
  const int rr1 = (t + 256) >> 3, cc1 = t & 7;    // rows 32..63

  bf16x8 qf[2];
  {
    const u16* qp = &Qg[(size_t)((bn << 10) + i0 + (w << 4) + l16) * 64 + lg * 8];
    qf[0] = *(const bf16x8*)qp;
    qf[1] = *(const bf16x8*)(qp + 32);
  }

  // ---- prologue: stage F high half (rows 64..127 of window 0, par=0) ----
  {
    int mb0 = i0 - 63;
    int h0 = 64 + rr0, h1 = 64 + rr1;
    int gm0 = mb0 + h0; gm0 = gm0 < 0 ? 0 : (gm0 > 1023 ? 1023 : gm0);
    int gm1 = mb0 + h1; gm1 = gm1 < 0 ? 0 : (gm1 > 1023 ? 1023 : gm1);
    u16x8 a = *(const u16x8*)&Fg[(size_t)((n << 10) + gm0) * 64 + cc0 * 8];
    u16x8 c = *(const u16x8*)&Fg[(size_t)((n << 10) + gm1) * 64 + cc1 * 8];
    *(u16x8*)&Fl[h0 * 64 + (((cc0 ^ (h0 & 7)) & 7) << 3)] = a;
    *(u16x8*)&Fl[h1 * 64 + (((cc1 ^ (h1 & 7)) & 7) << 3)] = c;
  }

  float mrun[4], lsum[4];
  f32x4 ao[4] = {};
#pragma unroll
  for (int r = 0; r < 4; ++r) { mrun[r] = -3.0e38f; lsum[r] = 0.0f; }

  u16x8 rk0, rk1, rv0, rv1, rf0, rf1;

#define LOAD_STAGE(jt_) do { \
    int j0_ = (jt_) * 64, mb_ = i0 - j0_ - 63; \
    rk0 = *(const u16x8*)&Kg[(size_t)((bn << 10) + j0_ + rr0) * 64 + cc0 * 8]; \
    rk1 = *(const u16x8*)&Kg[(size_t)((bn << 10) + j0_ + rr1) * 64 + cc1 * 8]; \
    rv0 = *(const u16x8*)&Vtg[(size_t)((bn << 6) + rr0) * 1024 + j0_ + cc0 * 8]; \
    rv1 = *(const u16x8*)&Vtg[(size_t)((bn << 6) + rr1) * 1024 + j0_ + cc1 * 8]; \
    int m0_ = mb_ + rr0; m0_ = m0_ < 0 ? 0 : (m0_ > 1023 ? 1023 : m0_); \
    int m1_ = mb_ + rr1; m1_ = m1_ < 0 ? 0 : (m1_ > 1023 ? 1023 : m1_); \
    rf0 = *(const u16x8*)&Fg[(size_t)((n << 10) + m0_) * 64 + cc0 * 8]; \
    rf1 = *(const u16x8*)&Fg[(size_t)((n << 10) + m1_) * 64 + cc1 * 8]; \
  } while (0)

  LOAD_STAGE(0);

  for (int jt = 0; jt <= qt; ++jt) {
    const bool diag = (jt == qt);
    const int ph = (jt & 1) << 6;      // F half-ring parity

    *(u16x8*)&Kl[rr0 * 64 + (((cc0 ^ (rr0 & 7)) & 7) << 3)] = rk0;
    *(u16x8*)&Kl[rr1 * 64 + (((cc1 ^ (rr1 & 7)) & 7) << 3)] = rk1;
    *(u16x8*)&Vl[rr0 * 64 + (((cc0 ^ (rr0 & 7)) & 7) << 3)] = rv0;
    *(u16x8*)&Vl[rr1 * 64 + (((cc1 ^ (rr1 & 7)) & 7) << 3)] = rv1;
    *(u16x8*)&Fl[(rr0 ^ ph) * 64 + (((cc0 ^ (rr0 & 7)) & 7) << 3)] = rf0;
    *(u16x8*)&Fl[(rr1 ^ ph) * 64 + (((cc1 ^ (rr1 & 7)) & 7) << 3)] = rf1;
    TOP_BARRIER();                     // lgkm drain + raw barrier (no vmcnt drain)

    if (jt < qt) LOAD_STAGE(jt + 1);   // in flight across the bottom barrier

    // ---- QK^T + band (MFMA cluster, setprio) ----
    __builtin_amdgcn_s_setprio(1);
    f32x4 sc[4] = {};
#pragma unroll
    for (int kk = 0; kk < 2; ++kk)
#pragma unroll
      for (int nn = 0; nn < 4; ++nn) {
        int jr = nn * 16 + l16;
        bf16x8 kb = *(const bf16x8*)&Kl[jr * 64 + ((((lg + 4 * kk) ^ (jr & 7)) & 7) << 3)];
        sc[nn] = MFMA16(qf[kk], kb, sc[nn]);
      }
    f32x4 bb[5] = {};
#pragma unroll
    for (int kk = 0; kk < 2; ++kk)
#pragma unroll
      for (int ct = 0; ct < 5; ++ct) {
        int trow = (w << 4) + ct * 16 + l16;
        bf16x8 fb = *(const bf16x8*)&Fl[(trow ^ ph) * 64 + ((((lg + 4 * kk) ^ (trow & 7)) & 7) << 3)];
        bb[ct] = MFMA16(qf[kk], fb, bb[ct]);
      }
    __builtin_amdgcn_s_setprio(0);

    // ---- scatter band to gathered layout ----
#pragma unroll
    for (int ct = 0; ct < 5; ++ct)
#pragma unroll
      for (int r = 0; r < 4; ++r) {
        int il = lg * 4 + r;
        int jl = il + 63 - (ct * 16 + l16);
        if ((unsigned)jl < 64u)
          BP[w][il * 64 + ((jl & 15) << 2) + (jl >> 4)] = f2b(bb[ct][r]);
      }
    WAVE_LDS_FENCE();

    // ---- assemble S; lane-local max; wave-level defer check ----
    float pv[4][4];
    float lmax[4];
#pragma unroll
    for (int r = 0; r < 4; ++r) {
      int il = lg * 4 + r;
      u16x4 gv = *(const u16x4*)&BP[w][il * 64 + (l16 << 2)];
      float m4 = -3.0e38f;
#pragma unroll
      for (int nn = 0; nn < 4; ++nn) {
        int jl = nn * 16 + l16;
        float s = sc[nn][r] + b2f(gv[nn]);
        if (diag && jl > (w << 4) + il) s = -1.0e30f;   // j > i
        pv[nn][r] = s;
        m4 = fmaxf(m4, s);
      }
      lmax[r] = m4;
    }
    bool ok = (lmax[0] <= mrun[0] + 8.0f) && (lmax[1] <= mrun[1] + 8.0f) &&
              (lmax[2] <= mrun[2] + 8.0f) && (lmax[3] <= mrun[3] + 8.0f);
    if (__all(ok)) {
#pragma unroll
      for (int r = 0; r < 4; ++r) {
        float rs = 0.0f;
#pragma unroll
        for (int nn = 0; nn < 4; ++nn) {
          pv[nn][r] = __expf(pv[nn][r] - mrun[r]);
          rs += pv[nn][r];
        }
        lsum[r] += rs;
      }
    } else {
#pragma unroll
      for (int r = 0; r < 4; ++r) {
        float mx = lmax[r];
#pragma unroll
        for (int off = 1; off < 16; off <<= 1) mx = fmaxf(mx, __shfl_xor(mx, off));
        float mnew = fmaxf(mrun[r], mx);
        float scl = __expf(mrun[r] - mnew);
        float rs = 0.0f;
#pragma unroll
        for (int nn = 0; nn < 4; ++nn) {
          pv[nn][r] = __expf(pv[nn][r] - mnew);
          rs += pv[nn][r];
        }
        lsum[r] = lsum[r] * scl + rs;
        mrun[r] = mnew;
#pragma unroll
        for (int nd = 0; nd < 4; ++nd) ao[nd][r] *= scl;
      }
    }

    // ---- P -> BP (swz layout), PV ----
#pragma unroll
    for (int nn = 0; nn < 4; ++nn)
#pragma unroll
      for (int r = 0; r < 4; ++r) {
        int i = lg * 4 + r, j = nn * 16 + l16;
        BP[w][i * 64 + ((((j >> 3) ^ (i & 7)) & 7) << 3) + (j & 7)] = f2b(pv[nn][r]);
      }
    WAVE_LDS_FENCE();
    __builtin_amdgcn_s_setprio(1);
#pragma unroll
    for (int kk = 0; kk < 2; ++kk) {
      bf16x8 pa = *(const bf16x8*)&BP[w][l16 * 64 + ((((lg + 4 * kk) ^ (l16 & 7)) & 7) << 3)];
#pragma unroll
      for (int nd = 0; nd < 4; ++nd) {
        int dr = nd * 16 + l16;
        bf16x8 vb = *(const bf16x8*)&Vl[dr * 64 + ((((lg + 4 * kk) ^ (dr & 7)) & 7) << 3)];
        ao[nd] = MFMA16(pa, vb, ao[nd]);
      }
    }
    __builtin_amdgcn_s_setprio(0);
    RAW_BARRIER();   // protect Kl/Vl/Fl (no vmcnt drain; prefetch survives)
  }

  // ---- finalize row sums, normalize + write ----
#pragma unroll
  for (int r = 0; r < 4; ++r)
#pragma unroll
    for (int off = 1; off < 16; off <<= 1) lsum[r] += __shfl_xor(lsum[r], off);

#pragma unroll
  for (int nd = 0; nd < 4; ++nd)
#pragma unroll
    for (int r = 0; r < 4; ++r) {
      int i = i0 + (w << 4) + lg * 4 + r;
      int d = nd * 16 + l16;
      float v = ao[nd][r] / lsum[r];
      AO[(size_t)((b << 10) + i) * 1024 + n * 64 + d] = f2b(v);
    }
#undef LOAD_STAGE
}

// ---------------- launch ----------------
extern "C" void kernel_launch(void* const* d_in, const int* in_sizes, int n_in,
                              void* d_out, int out_size, void* d_ws, size_t ws_size,
                              hipStream_t stream) {
  (void)in_sizes; (void)n_in; (void)out_size; (void)ws_size;
  const float* x    = (const float*)d_in[0];
  // d_in[1] = mask: always causal triu(k=1) -> analytic
  const float* Wqkv = (const float*)d_in[2];
  const float* bqkv = (const float*)d_in[3];
  const float* Wo   = (const float*)d_in[4];
  const float* bo   = (const float*)d_in[5];
  const float* Er   = (const float*)d_in[6];
  float* out = (float*)d_out;

  char* p = (char*)d_ws;
  u16* xb    = (u16*)p; p += (size_t)4096 * 1024 * 2;
  u16* wqkvb = (u16*)p; p += (size_t)3072 * 1024 * 2;
  u16* wob   = (u16*)p; p += (size_t)1024 * 1024 * 2;
  u16* Fb    = (u16*)p; p += (size_t)16 * 1024 * 64 * 2;
  u16* Qb    = (u16*)p; p += (size_t)64 * 1024 * 64 * 2;
  u16* Kb    = (u16*)p; p += (size_t)64 * 1024 * 64 * 2;
  u16* Vtb   = (u16*)p; p += (size_t)64 * 1024 * 64 * 2;   // V^T (bn, d, i)
  u16* AO    = (u16*)p; p += (size_t)4096 * 1024 * 2;

  cvt_all<<<9216, 256, 0, stream>>>(x, xb, Wqkv, wqkvb, Wo, wob, Er, Fb);
  gemm_qkv<<<dim3(24, 32), 256, 0, stream>>>(xb, wqkvb, bqkv, Qb, Kb, Vtb);
  attn_kernel<<<dim3(64, 16), 256, 0, stream>>>(Qb, Kb, Vtb, Fb, AO);
  gemm_out<<<dim3(8, 32), 256, 0, stream>>>(AO, wob, bo, out);
}